// Round 10
// baseline (37.080 us; speedup 1.0000x reference)
//
#include <hip/hip_runtime.h>
#include <math.h>

#define NN 320
#define DFULL 129            // 1 time dim + 128 spatial
#define MIN_DIST_F 0.1f
#define MARGIN_F 0.1f
#define WEIGHT_F 0.1f

// ---------------- Node 1: fused Gram row + ordered-pair loss -> partial[i] ----------------
// Block = anchor i (320 blocks x 320 threads). All phases bit-exact-proven in r6.
// Phase A: emb row i via 16-lane group dots. Lane q of group g reads Ej[q+16u]
//   (16 consecutive floats per group = one 64B line) -> E read once per block,
//   53 MB L2 traffic chip-wide. (Per-lane-own-row reads would be 845 MB / ~20us
//   -- the r3/r6-phaseA distinction, measured.)
// Phase B: thread t owns k = t; j-loop is wave-uniform LDS broadcast. NaN-poisoned
//   e kills invalid pairs via NaN-safe cndmask adds (never multiply-by-flag:
//   0*NaN=NaN). Self-pair j==k (exactly MARGIN) removed per-lane.
// Ordered-pair symmetry doubles total & count equally; ratio unchanged.
__global__ __launch_bounds__(NN) void fused_kernel(const float* __restrict__ E,
                                                   const float* __restrict__ gt,
                                                   float2* __restrict__ partial) {
    const int i = blockIdx.x;
    const int t = threadIdx.x;
    const int g = t >> 4;      // group 0..19
    const int q = t & 15;      // lane within group

    __shared__ float  sEi[DFULL];
    __shared__ float2 sge[NN];             // (e or NaN, gt value)

    if (t < DFULL) sEi[t] = E[i * DFULL + t];
    sge[t] = make_float2(0.0f, gt[i * NN + t]);   // coalesced gt row stage
    __syncthreads();

    const float e0   = sEi[0];
    const float e128 = sEi[128];

    // ---- Phase A: group g computes dots for j = g, g+20, ..., g+300 ----
    for (int j = g; j < NN; j += 20) {
        const float* __restrict__ Ej = E + j * DFULL;
        float S = 0.0f;
        #pragma unroll
        for (int u = 0; u < 8; ++u) {      // d = q + 16u  (covers 0..127)
            const int d = q + (u << 4);
            S = fmaf(sEi[d], Ej[d], S);
        }
        S += __shfl_xor(S, 1, 64);
        S += __shfl_xor(S, 2, 64);
        S += __shfl_xor(S, 4, 64);
        S += __shfl_xor(S, 8, 64);         // S = sum_{d=0..127} E_i[d]*E_j[d]
        if (q == 0) {
            // -inner = t_i t_j - sp_i.sp_j = 2*E_i0*E_j0 - S - E_i128*E_j128
            float x = fmaf(2.0f * e0, Ej[0], -S) - e128 * Ej[128];
            x = fmaxf(x, 1.0f + 1e-7f);
            float e  = acoshf(x);
            float gv = sge[j].y;
            bool valid = (gv >= MIN_DIST_F) && (j != i);
            sge[j].x = valid ? e : __builtin_nanf("");
        }
    }
    __syncthreads();

    // ---- Phase B: ordered-pair loss; this thread owns k = t ----
    const float2 me = sge[t];
    const float ek = me.x, gk = me.y;      // ek NaN iff k invalid for anchor i
    float tot = 0.0f, cnt = 0.0f;
    #pragma unroll 8
    for (int j = 0; j < NN; ++j) {
        float2 u = sge[j];                 // wave-uniform LDS broadcast
        float d  = gk - u.y;
        float s  = copysignf(1.0f, d);
        float v  = fmaf(s, u.x - ek, MARGIN_F);   // NaN if either side invalid
        bool p   = v > 0.0f;                      // false for NaN
        tot += p ? v : 0.0f;
        cnt += p ? 1.0f : 0.0f;
    }
    if (ek == ek) { tot -= MARGIN_F; cnt -= 1.0f; }   // self-pair j==k (= MARGIN)

    // block reduce (5 waves) -> plain store, no atomics, no gate
    for (int off = 32; off > 0; off >>= 1) {
        tot += __shfl_down(tot, off, 64);
        cnt += __shfl_down(cnt, off, 64);
    }
    __shared__ float wt[5], wc[5];
    const int lane = t & 63, wid = t >> 6;
    if (lane == 0) { wt[wid] = tot; wc[wid] = cnt; }
    __syncthreads();
    if (t == 0) {
        float T = wt[0] + wt[1] + wt[2] + wt[3] + wt[4];
        float C = wc[0] + wc[1] + wc[2] + wc[3] + wc[4];
        partial[i] = make_float2(T, C);
    }
}

// ---------------- Node 2: reduce 320 partials, finalize scalar loss ----------------
__global__ __launch_bounds__(NN) void finalize_kernel(const float2* __restrict__ partial,
                                                      float* __restrict__ out) {
    const int t = threadIdx.x;
    float2 p = partial[t];
    float T = p.x, C = p.y;
    for (int off = 32; off > 0; off >>= 1) {
        T += __shfl_down(T, off, 64);
        C += __shfl_down(C, off, 64);
    }
    __shared__ float wt[5], wc[5];
    const int lane = t & 63, wid = t >> 6;
    if (lane == 0) { wt[wid] = T; wc[wid] = C; }
    __syncthreads();
    if (t == 0) {
        float Tt = 0.0f, Ct = 0.0f;
        #pragma unroll
        for (int w = 0; w < 5; w++) { Tt += wt[w]; Ct += wc[w]; }
        out[0] = (Ct > 0.0f) ? WEIGHT_F * Tt / Ct : 0.0f;
    }
}

extern "C" void kernel_launch(void* const* d_in, const int* in_sizes, int n_in,
                              void* d_out, int out_size, void* d_ws, size_t ws_size,
                              hipStream_t stream) {
    const float* E  = (const float*)d_in[0];   // embeddings (320 x 129)
    const float* gt = (const float*)d_in[1];   // tree_distances (320 x 320)
    float* out = (float*)d_out;
    float2* partial = (float2*)d_ws;           // 320 float2 = 2.5 KB

    fused_kernel<<<NN, NN, 0, stream>>>(E, gt, partial);
    finalize_kernel<<<1, NN, 0, stream>>>(partial, out);
}

// Round 11
// 22.946 us; speedup vs baseline: 1.6159x; 1.6159x over previous
//
#include <hip/hip_runtime.h>
#include <math.h>

#define NN 320
#define DFULL 129            // 1 time dim + 128 spatial
#define MIN_DIST_F 0.1f
#define MARGIN_F 0.1f
#define WEIGHT_F 0.1f
#define NTILE 20             // 320/16
#define NTRI (NTILE*(NTILE+1)/2)  // 210 triangular tiles
#define JLEN 80              // j-chunk length
#define NCHUNK 14            // triangle-pruned (kg,jc) chunks per anchor
#define NPART (NN*NCHUNK)    // 4480 partials

// (kg,jc) for chunk y (only chunks whose j-range [80jc,80jc+80) intersects j>64kg):
// y : 0  1  2  3  4  5  6  7  8  9 10 11 12 13
// kg: 0  0  0  0  1  1  1  1  2  2  2  3  3  4
// jc: 0  1  2  3  0  1  2  3  1  2  3  2  3  3
#define KG_PACK 0x0043322211110000ULL
#define JC_PACK 0x0033232132103210ULL

// ---------------- Kernel 1: Lorentz distances, NaN-poisoned, symmetric (r5 verbatim) ----------------
__device__ __forceinline__ int tri_off(int a) { return a * NTILE - (a * (a - 1)) / 2; }

__global__ __launch_bounds__(256) void lorentz_kernel(const float* __restrict__ E,
                                                      const float* __restrict__ gt,
                                                      float* __restrict__ embp) {
    // decode triangular tile (a <= b)
    const int t = blockIdx.x;
    float fa = (2.0f * NTILE + 1.0f - sqrtf((2.0f*NTILE+1.0f)*(2.0f*NTILE+1.0f) - 8.0f * (float)t)) * 0.5f;
    int a = (int)fa;
    if (a > 0 && tri_off(a) > t) --a;
    if (tri_off(a + 1) <= t) ++a;
    const int b = a + (t - tri_off(a));
    const int i0 = a * 16, j0 = b * 16;

    __shared__ float As[16][DFULL];
    __shared__ float Bs[16][DFULL];
    for (int q = threadIdx.x; q < 16 * DFULL; q += 256) {
        int r = q / DFULL, c = q - r * DFULL;
        As[r][c] = E[(i0 + r) * DFULL + c];
        Bs[r][c] = E[(j0 + r) * DFULL + c];
    }
    __syncthreads();
    const int ti = threadIdx.x & 15;
    const int tj = threadIdx.x >> 4;
    const int i = i0 + tj, j = j0 + ti;
    float tt = As[tj][0] * Bs[ti][0];
    float ss = 0.0f;
    #pragma unroll
    for (int d = 1; d < DFULL; ++d) ss = fmaf(As[tj][d], Bs[ti][d], ss);
    float x = fmaxf(tt - ss, 1.0f + 1e-7f);
    float e = acoshf(x);
    float g = gt[i * NN + j];
    float ep = (g >= MIN_DIST_F && i != j) ? e : __builtin_nanf("");
    embp[i * NN + j] = ep;   // symmetric; diagonal tiles double-write same value (benign)
    embp[j * NN + i] = ep;
}

// ---------------- Kernel 2: TRIANGLE-only violations, one wave per (i,chunk) ----------------
// Lane owns k = kg*64+lane; j sweeps [80jc, 80jc+80) with per-term mask j > k
// (matches reference triu exactly; no self-pair, no double-count, no correction).
// NaN-poisoned embp kills invalid pairs: v NaN -> (v>0) false -> cndmask adds 0
// (never multiply-by-flag: 0*NaN=NaN). count accumulates wave-uniformly via
// __popcll(__ballot(p)) (SALU, overlaps VALU; no lane reduce for cnt).
__global__ __launch_bounds__(64) void loss_kernel(const float* __restrict__ embp,
                                                  const float* __restrict__ gt,
                                                  float2* __restrict__ partial) {
    const int i    = blockIdx.x;                 // anchor
    const int y    = blockIdx.y;                 // chunk id 0..13
    const int kg   = (int)((KG_PACK >> (4 * y)) & 0xF);
    const int jc   = (int)((JC_PACK >> (4 * y)) & 0xF);
    const int lane = threadIdx.x;
    const int k    = (kg << 6) + lane;

    const float* __restrict__ erow = embp + i * NN;
    const float* __restrict__ grow = gt   + i * NN;
    const float ek = erow[k];                    // NaN if k invalid for anchor i
    const float gk = grow[k];
    const int j0 = jc * JLEN;

    float tot = 0.0f;
    int   cnt = 0;
    #pragma unroll
    for (int jb = 0; jb < JLEN; jb += 4) {
        const float4 e4 = *reinterpret_cast<const float4*>(erow + j0 + jb);
        const float4 g4 = *reinterpret_cast<const float4*>(grow + j0 + jb);
        {   const int j = j0 + jb;
            float d = gk - g4.x; float v = fmaf(copysignf(1.0f, d), e4.x - ek, MARGIN_F);
            bool p = (v > 0.0f) && (j > k); tot += p ? v : 0.0f; cnt += (int)__popcll(__ballot(p)); }
        {   const int j = j0 + jb + 1;
            float d = gk - g4.y; float v = fmaf(copysignf(1.0f, d), e4.y - ek, MARGIN_F);
            bool p = (v > 0.0f) && (j > k); tot += p ? v : 0.0f; cnt += (int)__popcll(__ballot(p)); }
        {   const int j = j0 + jb + 2;
            float d = gk - g4.z; float v = fmaf(copysignf(1.0f, d), e4.z - ek, MARGIN_F);
            bool p = (v > 0.0f) && (j > k); tot += p ? v : 0.0f; cnt += (int)__popcll(__ballot(p)); }
        {   const int j = j0 + jb + 3;
            float d = gk - g4.w; float v = fmaf(copysignf(1.0f, d), e4.w - ek, MARGIN_F);
            bool p = (v > 0.0f) && (j > k); tot += p ? v : 0.0f; cnt += (int)__popcll(__ballot(p)); }
    }

    // lane reduce (tot only; cnt is wave-uniform via ballot)
    for (int off = 32; off > 0; off >>= 1) tot += __shfl_down(tot, off, 64);
    if (lane == 0) partial[y * NN + i] = make_float2(tot, (float)cnt);
}

// ---------------- Kernel 3: reduce 4480 partials, finalize ----------------
__global__ __launch_bounds__(NN) void finalize_kernel(const float2* __restrict__ partial,
                                                      float* __restrict__ out) {
    const int t = threadIdx.x;
    float T = 0.0f, C = 0.0f;
    #pragma unroll
    for (int q = 0; q < NCHUNK; ++q) {           // 14 coalesced float2 reads
        float2 p = partial[q * NN + t];
        T += p.x; C += p.y;
    }
    for (int off = 32; off > 0; off >>= 1) {
        T += __shfl_down(T, off, 64);
        C += __shfl_down(C, off, 64);
    }
    __shared__ float wt[5], wc[5];
    const int lane = t & 63, wid = t >> 6;
    if (lane == 0) { wt[wid] = T; wc[wid] = C; }
    __syncthreads();
    if (t == 0) {
        float Tt = 0.0f, Ct = 0.0f;
        #pragma unroll
        for (int w = 0; w < 5; w++) { Tt += wt[w]; Ct += wc[w]; }
        out[0] = (Ct > 0.0f) ? WEIGHT_F * Tt / Ct : 0.0f;
    }
}

extern "C" void kernel_launch(void* const* d_in, const int* in_sizes, int n_in,
                              void* d_out, int out_size, void* d_ws, size_t ws_size,
                              hipStream_t stream) {
    const float* E  = (const float*)d_in[0];   // embeddings (320 x 129)
    const float* gt = (const float*)d_in[1];   // tree_distances (320 x 320)
    float* out = (float*)d_out;
    float2* partial = (float2*)d_ws;                      // 4480 float2 = 35.8 KB
    float*  embp = (float*)((char*)d_ws + 65536);         // 320*320 f32 = 400 KB

    lorentz_kernel<<<NTRI, 256, 0, stream>>>(E, gt, embp);
    dim3 g2(NN, NCHUNK);
    loss_kernel<<<g2, 64, 0, stream>>>(embp, gt, partial);
    finalize_kernel<<<1, NN, 0, stream>>>(partial, out);
}